// Round 7
// baseline (191.234 us; speedup 1.0000x reference)
//
#include <hip/hip_runtime.h>
#include <hip/hip_bf16.h>
#include <math.h>
#include <stdint.h>

#define B_N   512
#define D_N   768
#define R_N   128
#define C_NEW 10
#define C_OLD 100
#define C_TOT 110
#define MARGIN_F    5.0f
#define VAR_FLOOR_F 1e-4f
#define BIG_F       1e6f

typedef __bf16 bf16;
typedef __bf16 bf16x4 __attribute__((ext_vector_type(4)));
typedef __bf16 bf16x8 __attribute__((ext_vector_type(8)));
typedef float  f32x4  __attribute__((ext_vector_type(4)));

__device__ __forceinline__ float cleanf(float v) { return isfinite(v) ? v : 0.0f; }

// Direct global->LDS 16B-per-lane async copy (wave-uniform LDS base + lane*16).
__device__ __forceinline__ void gld16(const bf16* g, bf16* l) {
    __builtin_amdgcn_global_load_lds(
        (const __attribute__((address_space(1))) unsigned int*)g,
        (__attribute__((address_space(3))) unsigned int*)l, 16, 0, 0);
}

// ---------------------------------------------------------------------------
// prep_fused: grid 462 x 256.
//  [0,128):   prep_z  (clean z -> bf16, znorm)
//  [128,458): bases third: pb = bid-128, c = pb/3, part = pb%3 (256 d each):
//             transpose+cast -> basesT, Gram partial -> f32 atomics,
//             m_c / munorm partials -> atomics. Targets pre-zeroed.
//  [458,462): zdotmu tile zt = bid-458: zdotmu[zt*128..+128][0..110) =
//             clean(z) . mu^T  via MFMA (bf16), f32 out.
// ---------------------------------------------------------------------------
__global__ __launch_bounds__(256)
void prep_fused(const float* __restrict__ z,
                const float* __restrict__ cur_bases, const float* __restrict__ old_bases,
                const float* __restrict__ cur_means, const float* __restrict__ old_means,
                bf16* __restrict__ zbf, float* __restrict__ znorm,
                bf16* __restrict__ basesT, float* __restrict__ Gacc,
                float* __restrict__ m_c, float* __restrict__ munorm,
                float* __restrict__ zdotmu)
{
    const int tid = threadIdx.x, wave = tid >> 6, lane = tid & 63;
    __shared__ __align__(16) unsigned char sm[36864];

    if (blockIdx.x < 128) {
        // ---------------- prep_z ----------------
        const int b = blockIdx.x * 4 + wave;
        const float4* src = (const float4*)(z + (size_t)b * D_N);
        bf16x4* dst = (bf16x4*)(zbf + (size_t)b * D_N);
        float nrm = 0.f;
        #pragma unroll
        for (int i = 0; i < 3; ++i) {
            float4 v = src[lane + i * 64];
            v.x = cleanf(v.x); v.y = cleanf(v.y); v.z = cleanf(v.z); v.w = cleanf(v.w);
            nrm += v.x * v.x + v.y * v.y + v.z * v.z + v.w * v.w;
            bf16x4 w;
            w[0] = (bf16)v.x; w[1] = (bf16)v.y; w[2] = (bf16)v.z; w[3] = (bf16)v.w;
            dst[lane + i * 64] = w;
        }
        #pragma unroll
        for (int off = 32; off >= 1; off >>= 1) nrm += __shfl_xor(nrm, off, 64);
        if (lane == 0) znorm[b] = nrm;
        return;
    }

    const int quad = lane >> 4, l15 = lane & 15;
    const int wr = (wave >> 1) * 64, wcn = (wave & 1) * 64;

    if (blockIdx.x >= 458) {
        // ---------------- zdotmu tile ----------------
        const int zt = blockIdx.x - 458;
        const int b0 = zt * 128;
        bf16* sZ = (bf16*)sm;            // [128][64]
        bf16* sU = (bf16*)(sm + 16384);  // [128][64] (class rows; >=110 zero)

        f32x4 acc[4][4];
        #pragma unroll
        for (int i = 0; i < 4; ++i)
            #pragma unroll
            for (int j = 0; j < 4; ++j) acc[i][j] = (f32x4)0.0f;

        for (int k0 = 0; k0 < D_N; k0 += 64) {
            __syncthreads();
            #pragma unroll
            for (int p = 0; p < 8; ++p) {
                int q = p * 256 + tid;
                int row = q >> 4, col4 = (q & 15) * 4;
                float4 v = *(const float4*)(z + (size_t)(b0 + row) * D_N + k0 + col4);
                bf16x4 w;
                w[0] = (bf16)cleanf(v.x); w[1] = (bf16)cleanf(v.y);
                w[2] = (bf16)cleanf(v.z); w[3] = (bf16)cleanf(v.w);
                *(bf16x4*)(sZ + row * 64 + col4) = w;
            }
            #pragma unroll
            for (int p = 0; p < 8; ++p) {
                int q = p * 256 + tid;
                int row = q >> 4, col4 = (q & 15) * 4;
                bf16x4 w;
                if (row < C_TOT) {
                    const float* mp = (row < C_NEW) ? cur_means + (size_t)row * D_N
                                                    : old_means + (size_t)(row - C_NEW) * D_N;
                    float4 v = *(const float4*)(mp + k0 + col4);
                    w[0] = (bf16)v.x; w[1] = (bf16)v.y; w[2] = (bf16)v.z; w[3] = (bf16)v.w;
                } else {
                    w[0] = (bf16)0.f; w[1] = (bf16)0.f; w[2] = (bf16)0.f; w[3] = (bf16)0.f;
                }
                *(bf16x4*)(sU + row * 64 + col4) = w;
            }
            __syncthreads();
            #pragma unroll
            for (int kk = 0; kk < 64; kk += 32) {
                bf16x8 af[4], bg[4];
                #pragma unroll
                for (int i = 0; i < 4; ++i) af[i] = *(const bf16x8*)(sZ + (wr + 16 * i + l15) * 64 + kk + quad * 8);
                #pragma unroll
                for (int j = 0; j < 4; ++j) bg[j] = *(const bf16x8*)(sU + (wcn + 16 * j + l15) * 64 + kk + quad * 8);
                #pragma unroll
                for (int i = 0; i < 4; ++i)
                    #pragma unroll
                    for (int j = 0; j < 4; ++j)
                        acc[i][j] = __builtin_amdgcn_mfma_f32_16x16x32_bf16(af[i], bg[j], acc[i][j], 0, 0, 0);
            }
        }
        #pragma unroll
        for (int i = 0; i < 4; ++i)
            #pragma unroll
            for (int j = 0; j < 4; ++j)
                #pragma unroll
                for (int reg = 0; reg < 4; ++reg) {
                    int row = wr + 16 * i + quad * 4 + reg;   // batch
                    int col = wcn + 16 * j + l15;             // class
                    if (col < C_TOT)
                        zdotmu[(size_t)(b0 + row) * C_TOT + col] = acc[i][j][reg];
                }
        return;
    }

    // ---------------- bases third ----------------
    const int pb = blockIdx.x - 128;
    const int c = pb / 3, part = pb % 3;
    const float* Bc = (c < C_NEW) ? cur_bases + (size_t)c * D_N * R_N
                                  : old_bases + (size_t)(c - C_NEW) * D_N * R_N;
    const float* mu = (c < C_NEW) ? cur_means + (size_t)c * D_N
                                  : old_means + (size_t)(c - C_NEW) * D_N;

    bf16 (*T)[136] = (bf16(*)[136])sm;            // 34816 B
    float* sMu  = (float*)(sm + 34816);           // 256 f32 (this part's slice)
    float* sRed = (float*)(sm + 34816 + 1024);    // 256 f32

    const int dbase = part * 256;

    {
        float v = mu[dbase + tid];
        sMu[tid] = v;
        float mn = v * v;
        #pragma unroll
        for (int off = 32; off >= 1; off >>= 1) mn += __shfl_xor(mn, off, 64);
        if (lane == 0) sRed[wave] = mn;
    }
    __syncthreads();
    if (tid == 0) atomicAdd(&munorm[c], sRed[0] + sRed[1] + sRed[2] + sRed[3]);

    float mcAcc = 0.f;
    const int mr = tid & 127, mdh = tid >> 7;

    f32x4 acc[4][4];
    #pragma unroll
    for (int i = 0; i < 4; ++i)
        #pragma unroll
        for (int j = 0; j < 4; ++j) acc[i][j] = (f32x4)0.0f;

    for (int ch = 0; ch < 2; ++ch) {
        const int d0 = dbase + ch * 128;
        __syncthreads();
        #pragma unroll
        for (int m = 0; m < 2; ++m) {
            int u = m * 256 + tid;
            int r4 = (u & 31) * 4;
            int dg = u >> 5;
            float4 v[8];
            #pragma unroll
            for (int j = 0; j < 8; ++j)
                v[j] = *(const float4*)(Bc + (size_t)(d0 + dg * 8 + j) * R_N + r4);
            #pragma unroll
            for (int i = 0; i < 4; ++i) {
                bf16x8 w;
                #pragma unroll
                for (int j = 0; j < 8; ++j) {
                    float f = (i == 0) ? v[j].x : (i == 1) ? v[j].y : (i == 2) ? v[j].z : v[j].w;
                    w[j] = (bf16)f;
                }
                *(bf16x8*)&T[r4 + i][dg * 8] = w;
            }
        }
        __syncthreads();
        {
            int r = tid >> 1, hf = tid & 1;
            const uint4* srcp = (const uint4*)&T[r][hf * 64];
            uint4* dstp = (uint4*)(basesT + (size_t)c * R_N * D_N + (size_t)r * D_N + d0 + hf * 64);
            #pragma unroll
            for (int m2 = 0; m2 < 8; ++m2) dstp[m2] = srcp[m2];
        }
        #pragma unroll 8
        for (int k = 0; k < 64; ++k)
            mcAcc += sMu[ch * 128 + mdh * 64 + k] * (float)T[mr][mdh * 64 + k];
        #pragma unroll
        for (int kk = 0; kk < 128; kk += 32) {
            bf16x8 af[4], bg[4];
            #pragma unroll
            for (int i = 0; i < 4; ++i) af[i] = *(const bf16x8*)&T[wr + 16 * i + l15][kk + quad * 8];
            #pragma unroll
            for (int j = 0; j < 4; ++j) bg[j] = *(const bf16x8*)&T[wcn + 16 * j + l15][kk + quad * 8];
            #pragma unroll
            for (int i = 0; i < 4; ++i)
                #pragma unroll
                for (int j = 0; j < 4; ++j)
                    acc[i][j] = __builtin_amdgcn_mfma_f32_16x16x32_bf16(af[i], bg[j], acc[i][j], 0, 0, 0);
        }
    }
    __syncthreads();
    sRed[tid] = mcAcc;
    __syncthreads();
    if (tid < 128) atomicAdd(&m_c[c * R_N + tid], sRed[tid] + sRed[128 + tid]);

    #pragma unroll
    for (int i = 0; i < 4; ++i)
        #pragma unroll
        for (int j = 0; j < 4; ++j)
            #pragma unroll
            for (int reg = 0; reg < 4; ++reg) {
                int r = wr + 16 * i + quad * 4 + reg;
                int s = wcn + 16 * j + l15;
                atomicAdd(&Gacc[(size_t)c * 16384 + (size_t)r * 128 + s], acc[i][j][reg]);
            }
}

// ---------------------------------------------------------------------------
// main_dist: coeff = z*B - m_c (MFMA), par/cnorm, H = coeff*G (MFMA), qsum,
// dist (zdotmu precomputed). grid (4, 110) x 256.
// ---------------------------------------------------------------------------
#define PADC 136
#define SM_AB  0                       // sA 16384 | sB 16384 ; sG 32768 (reuse)
#define SM_C   32768                   // 34816
#define SM_M   67584
#define SM_INV 68096
#define SM_PAR 68608
#define SM_CN  69120
#define SM_Q   69632
#define SM_T2  70144                   // 512 f32 (par|cn)
#define SM_SZ  72192

__global__ __launch_bounds__(256, 2)
void main_dist(const bf16* __restrict__ zbf, const bf16* __restrict__ basesT,
               const float* __restrict__ Gacc, const float* __restrict__ m_c,
               const float* __restrict__ cur_vars, const float* __restrict__ old_vars,
               const float* __restrict__ znorm, const float* __restrict__ munorm,
               const float* __restrict__ zdotmu, float* __restrict__ gdist)
{
    const int mt = blockIdx.x, c = blockIdx.y;
    const int b0 = mt * 128;
    const float* vars = (c < C_NEW) ? cur_vars + (size_t)c * (R_N + 1)
                                    : old_vars + (size_t)(c - C_NEW) * (R_N + 1);
    __shared__ __align__(16) unsigned char smem[SM_SZ];
    bf16*  sA   = (bf16*)(smem + SM_AB);
    bf16*  sB   = (bf16*)(smem + SM_AB + 16384);
    bf16*  sG   = (bf16*)(smem + SM_AB);          // reused after GEMM1
    bf16*  sC   = (bf16*)(smem + SM_C);
    float* sM   = (float*)(smem + SM_M);
    float* sInv = (float*)(smem + SM_INV);
    float* sPar = (float*)(smem + SM_PAR);
    float* sCn  = (float*)(smem + SM_CN);
    float* sQ   = (float*)(smem + SM_Q);
    float* sT2  = (float*)(smem + SM_T2);

    const int tid = threadIdx.x, wave = tid >> 6, lane = tid & 63;
    const int quad = lane >> 4, l15 = lane & 15;
    const int wr = (wave >> 1) * 64, wc = (wave & 1) * 64;

    if (tid < 128) {
        sM[tid]   = m_c[c * R_N + tid];
        sInv[tid] = 1.0f / fmaxf(vars[tid], VAR_FLOOR_F);
        sQ[tid]   = 0.0f;
    }

    // ---- GEMM1: coeff_raw = z_tile * B_c (pure stage + MFMA) ----
    f32x4 acc1[4][4];
    #pragma unroll
    for (int i = 0; i < 4; ++i)
        #pragma unroll
        for (int j = 0; j < 4; ++j) acc1[i][j] = (f32x4)0.0f;

    const bf16* Az = zbf + (size_t)b0 * D_N;
    const bf16* Bb = basesT + (size_t)c * R_N * D_N;
    const int rl = lane >> 3;     // row within 8-row staging group
    const int cl = lane & 7;      // 16B col unit within 128B row

    for (int k0 = 0; k0 < D_N; k0 += 64) {
        __syncthreads();
        #pragma unroll
        for (int j = 0; j < 4; ++j) {
            int r0 = j * 32 + wave * 8;                    // wave-uniform
            gld16(Az + (size_t)(r0 + rl) * D_N + k0 + cl * 8, sA + r0 * 64);
            gld16(Bb + (size_t)(r0 + rl) * D_N + k0 + cl * 8, sB + r0 * 64);
        }
        __syncthreads();
        #pragma unroll
        for (int kk = 0; kk < 64; kk += 32) {
            bf16x8 af[4], bg[4];
            #pragma unroll
            for (int i = 0; i < 4; ++i) af[i] = *(const bf16x8*)(sA + (wr + 16 * i + l15) * 64 + kk + quad * 8);
            #pragma unroll
            for (int j = 0; j < 4; ++j) bg[j] = *(const bf16x8*)(sB + (wc + 16 * j + l15) * 64 + kk + quad * 8);
            #pragma unroll
            for (int i = 0; i < 4; ++i)
                #pragma unroll
                for (int j = 0; j < 4; ++j)
                    acc1[i][j] = __builtin_amdgcn_mfma_f32_16x16x32_bf16(af[i], bg[j], acc1[i][j], 0, 0, 0);
        }
    }

    // ---- subtract m_c; keep f32 in regs; write bf16 coeff to sC ----
    #pragma unroll
    for (int j = 0; j < 4; ++j) {
        float mcv = sM[wc + 16 * j + l15];
        #pragma unroll
        for (int i = 0; i < 4; ++i)
            #pragma unroll
            for (int reg = 0; reg < 4; ++reg) {
                float cv = acc1[i][j][reg] - mcv;
                acc1[i][j][reg] = cv;
                int row = wr + 16 * i + quad * 4 + reg;
                int col = wc + 16 * j + l15;
                sC[row * PADC + col] = (bf16)cv;
            }
    }
    __syncthreads();

    // ---- par / cnorm per row (from bf16 coeff) + stage G (f32->bf16) ----
    {
        int row = tid >> 1, half = tid & 1;
        float par = 0.f, cn = 0.f;
        #pragma unroll
        for (int m = 0; m < 8; ++m) {
            bf16x8 v = *(const bf16x8*)(sC + row * PADC + half * 64 + m * 8);
            #pragma unroll
            for (int e = 0; e < 8; ++e) {
                float f = (float)v[e];
                int col = half * 64 + m * 8 + e;
                cn  += f * f;
                par += f * f * sInv[col];
            }
        }
        sT2[tid] = par;
        sT2[256 + tid] = cn;
    }
    {
        const float* Gc = Gacc + (size_t)c * 16384;
        #pragma unroll
        for (int m = 0; m < 16; ++m) {
            int idx = (m * 256 + tid) * 4;
            float4 v = *(const float4*)(Gc + idx);
            bf16x4 w;
            w[0] = (bf16)v.x; w[1] = (bf16)v.y; w[2] = (bf16)v.z; w[3] = (bf16)v.w;
            *(bf16x4*)(sG + idx) = w;
        }
    }
    __syncthreads();
    if (tid < 128) {
        sPar[tid] = sT2[tid * 2] + sT2[tid * 2 + 1];
        sCn[tid]  = sT2[256 + tid * 2] + sT2[256 + tid * 2 + 1];
    }

    // ---- GEMM2: H = coeff * G  (K=128), sG [128][128] (G symmetric) ----
    f32x4 acc2[4][4];
    #pragma unroll
    for (int i = 0; i < 4; ++i)
        #pragma unroll
        for (int j = 0; j < 4; ++j) acc2[i][j] = (f32x4)0.0f;
    #pragma unroll
    for (int kc = 0; kc < 128; kc += 32) {
        bf16x8 af[4], bg[4];
        #pragma unroll
        for (int i = 0; i < 4; ++i) af[i] = *(const bf16x8*)(sC + (wr + 16 * i + l15) * PADC + kc + quad * 8);
        #pragma unroll
        for (int j = 0; j < 4; ++j) bg[j] = *(const bf16x8*)(sG + (wc + 16 * j + l15) * 128 + kc + quad * 8);
        #pragma unroll
        for (int i = 0; i < 4; ++i)
            #pragma unroll
            for (int j = 0; j < 4; ++j)
                acc2[i][j] = __builtin_amdgcn_mfma_f32_16x16x32_bf16(af[i], bg[j], acc2[i][j], 0, 0, 0);
    }

    // ---- qsum[row] = sum_s H[row][s] * coeff[row][s] ----
    #pragma unroll
    for (int i = 0; i < 4; ++i)
        #pragma unroll
        for (int reg = 0; reg < 4; ++reg) {
            float qp = 0.f;
            #pragma unroll
            for (int j = 0; j < 4; ++j) qp += acc2[i][j][reg] * acc1[i][j][reg];
            qp += __shfl_xor(qp, 1, 64);
            qp += __shfl_xor(qp, 2, 64);
            qp += __shfl_xor(qp, 4, 64);
            qp += __shfl_xor(qp, 8, 64);
            if (l15 == 0) atomicAdd(&sQ[wr + 16 * i + quad * 4 + reg], qp);
        }
    __syncthreads();

    // ---- final dist per row ----
    if (tid < 128) {
        int b = b0 + tid;
        float zdot = zdotmu[(size_t)b * C_TOT + c];
        float nd2 = znorm[b] - 2.0f * zdot + munorm[c];
        float res = fmaxf(vars[R_N], VAR_FLOOR_F);
        float dist = (sPar[tid] + (nd2 - 2.0f * sCn[tid] + sQ[tid]) / res) / (float)D_N;
        if (!isfinite(dist)) dist = BIG_F;
        gdist[(size_t)b * C_TOT + c] = dist;
    }
}

// ---------------------------------------------------------------------------
// finalize: single block, 512 threads (one per batch row), LDS accumulators.
// ---------------------------------------------------------------------------
__global__ __launch_bounds__(512)
void finalize(const float* __restrict__ gdist,
              const int* __restrict__ labels,
              const int* __restrict__ ncid,
              float* __restrict__ out)
{
    __shared__ float sAcc[C_NEW * 4];
    const int tid = threadIdx.x;
    if (tid < C_NEW * 4) sAcc[tid] = 0.f;
    __syncthreads();

    const float* row = gdist + (size_t)tid * C_TOT;
    float mn = 3.4e38f;
    #pragma unroll
    for (int cc = C_NEW; cc < C_TOT; ++cc) mn = fminf(mn, row[cc]);
    const int lab = labels[tid];
    #pragma unroll
    for (int k = 0; k < C_NEW; ++k) {
        if (lab == ncid[k]) {
            int col = min(max(ncid[k], 0), C_TOT - 1);
            float ow = row[col];
            atomicAdd(&sAcc[k * 4 + 0], 1.0f);
            atomicAdd(&sAcc[k * 4 + 1], fmaxf(0.0f, MARGIN_F + ow - mn));
            atomicAdd(&sAcc[k * 4 + 2], ow);
            atomicAdd(&sAcc[k * 4 + 3], mn);
        }
    }
    __syncthreads();
    if (tid == 0) {
        float total = 0.f, own = 0.f, old = 0.f, nv = 0.f;
        #pragma unroll
        for (int k = 0; k < C_NEW; ++k) {
            float cnt = sAcc[k * 4 + 0];
            float den = fmaxf(cnt, 1.0f);
            if (cnt > 0.f) {
                nv += 1.f;
                total += sAcc[k * 4 + 1] / den;
                own   += sAcc[k * 4 + 2] / den;
                old   += sAcc[k * 4 + 3] / den;
            }
        }
        float nvd = fmaxf(nv, 1.0f);
        out[0] = total / nvd;
        out[1] = own / nvd;
        out[2] = old / nvd;
    }
}

// ---------------------------------------------------------------------------
// workspace layout (bytes):
//   gdist  @ 0        : 225280
//   zbf    @ 225280   : 786432
//   znorm  @ 1011712  : 2048
//   munorm @ 1013760  : 512      \
//   m_c    @ 1014272  : 56320     > one contiguous memset: [1013760, 8279552)
//   Gacc   @ 1070592  : 7208960  /
//   basesT @ 8279552  : 21626880
//   zdotmu @ 29906432 : 225280   -> total ~30.1 MB
// ---------------------------------------------------------------------------
extern "C" void kernel_launch(void* const* d_in, const int* in_sizes, int n_in,
                              void* d_out, int out_size, void* d_ws, size_t ws_size,
                              hipStream_t stream)
{
    const float* features  = (const float*)d_in[0];
    const int*   labels    = (const int*)d_in[1];
    const int*   ncid      = (const int*)d_in[2];
    const float* cur_means = (const float*)d_in[3];
    const float* cur_bases = (const float*)d_in[4];
    const float* cur_vars  = (const float*)d_in[5];
    const float* old_means = (const float*)d_in[6];
    const float* old_bases = (const float*)d_in[7];
    const float* old_vars  = (const float*)d_in[8];

    unsigned char* ws = (unsigned char*)d_ws;
    float* gdist  = (float*)(ws + 0);
    bf16*  zbf    = (bf16*) (ws + 225280);
    float* znorm  = (float*)(ws + 1011712);
    float* munorm = (float*)(ws + 1013760);
    float* m_c    = (float*)(ws + 1014272);
    float* Gacc   = (float*)(ws + 1070592);
    bf16*  basesT = (bf16*) (ws + 8279552);
    float* zdotmu = (float*)(ws + 29906432);

    hipMemsetAsync(munorm, 0, 512 + 56320 + 7208960, stream);  // munorm+m_c+Gacc

    prep_fused<<<dim3(128 + 3 * C_TOT + 4), dim3(256), 0, stream>>>(
        features, cur_bases, old_bases, cur_means, old_means,
        zbf, znorm, basesT, Gacc, m_c, munorm, zdotmu);
    main_dist<<<dim3(4, C_TOT), dim3(256), 0, stream>>>(zbf, basesT, Gacc, m_c,
                                                        cur_vars, old_vars,
                                                        znorm, munorm, zdotmu, gdist);
    finalize<<<dim3(1), dim3(512), 0, stream>>>(gdist, labels, ncid, (float*)d_out);
}

// Round 8
// 162.143 us; speedup vs baseline: 1.1794x; 1.1794x over previous
//
#include <hip/hip_runtime.h>
#include <hip/hip_bf16.h>
#include <math.h>
#include <stdint.h>

#define B_N   512
#define D_N   768
#define R_N   128
#define C_NEW 10
#define C_OLD 100
#define C_TOT 110
#define MARGIN_F    5.0f
#define VAR_FLOOR_F 1e-4f
#define BIG_F       1e6f

typedef __bf16 bf16;
typedef __bf16 bf16x4 __attribute__((ext_vector_type(4)));
typedef __bf16 bf16x8 __attribute__((ext_vector_type(8)));
typedef float  f32x4  __attribute__((ext_vector_type(4)));

__device__ __forceinline__ float cleanf(float v) { return isfinite(v) ? v : 0.0f; }

// ---------------------------------------------------------------------------
// prep_zmu: grid 238 x 256.
//  [0,128):   clean z -> bf16 copy + znorm[b] (wave per row)
//  [128,238): munorm[c] = ||mu_c||^2
// ---------------------------------------------------------------------------
__global__ __launch_bounds__(256)
void prep_zmu(const float* __restrict__ z,
              const float* __restrict__ cur_means, const float* __restrict__ old_means,
              bf16* __restrict__ zbf, float* __restrict__ znorm, float* __restrict__ munorm)
{
    const int tid = threadIdx.x, wave = tid >> 6, lane = tid & 63;
    __shared__ float s[4];

    if (blockIdx.x < 128) {
        const int b = blockIdx.x * 4 + wave;
        const float4* src = (const float4*)(z + (size_t)b * D_N);
        bf16x4* dst = (bf16x4*)(zbf + (size_t)b * D_N);
        float nrm = 0.f;
        #pragma unroll
        for (int i = 0; i < 3; ++i) {
            float4 v = src[lane + i * 64];
            v.x = cleanf(v.x); v.y = cleanf(v.y); v.z = cleanf(v.z); v.w = cleanf(v.w);
            nrm += v.x * v.x + v.y * v.y + v.z * v.z + v.w * v.w;
            bf16x4 w;
            w[0] = (bf16)v.x; w[1] = (bf16)v.y; w[2] = (bf16)v.z; w[3] = (bf16)v.w;
            dst[lane + i * 64] = w;
        }
        #pragma unroll
        for (int off = 32; off >= 1; off >>= 1) nrm += __shfl_xor(nrm, off, 64);
        if (lane == 0) znorm[b] = nrm;
        return;
    }

    const int c = blockIdx.x - 128;
    const float* mu = (c < C_NEW) ? cur_means + (size_t)c * D_N
                                  : old_means + (size_t)(c - C_NEW) * D_N;
    float p = 0.f;
    for (int d = tid; d < D_N; d += 256) p += mu[d] * mu[d];
    #pragma unroll
    for (int off = 32; off >= 1; off >>= 1) p += __shfl_xor(p, off, 64);
    if (lane == 0) s[wave] = p;
    __syncthreads();
    if (tid == 0) munorm[c] = s[0] + s[1] + s[2] + s[3];
}

// ---------------------------------------------------------------------------
// transpose_mc: basesT[c][r][d] (bf16) from bases[c][d][r] (f32), plus
// m_c[c][r] += sum_d mu[d]*B[d][r] (atomic, m_c pre-zeroed).
// grid (6, 110), block 256. Tile: 128 d x 128 r.
// ---------------------------------------------------------------------------
__global__ __launch_bounds__(256)
void transpose_mc(const float* __restrict__ cur_bases, const float* __restrict__ old_bases,
                  const float* __restrict__ cur_means, const float* __restrict__ old_means,
                  bf16* __restrict__ basesT, float* __restrict__ m_c)
{
    const int dt = blockIdx.x, c = blockIdx.y;
    const float* Bc = (c < C_NEW) ? cur_bases + (size_t)c * D_N * R_N
                                  : old_bases + (size_t)(c - C_NEW) * D_N * R_N;
    const float* mu = (c < C_NEW) ? cur_means + (size_t)c * D_N
                                  : old_means + (size_t)(c - C_NEW) * D_N;
    __shared__ bf16 T[128][132];
    __shared__ float sMu[128];
    const int t = threadIdx.x;
    const int d0 = dt * 128;
    if (t < 128) sMu[t] = mu[d0 + t];

    #pragma unroll 4
    for (int it = 0; it < 16; ++it) {
        int q = it * 256 + t;
        int d = q >> 5, rr = (q & 31) * 4;
        float4 v = *(const float4*)(Bc + (size_t)(d0 + d) * R_N + rr);
        T[rr + 0][d] = (bf16)v.x;
        T[rr + 1][d] = (bf16)v.y;
        T[rr + 2][d] = (bf16)v.z;
        T[rr + 3][d] = (bf16)v.w;
    }
    __syncthreads();

    #pragma unroll 4
    for (int it = 0; it < 16; ++it) {
        int q = it * 256 + t;
        int r = q >> 5, dd = (q & 31) * 4;
        ushort4 w = *(const ushort4*)&T[r][dd];
        *(ushort4*)(basesT + (size_t)c * R_N * D_N + (size_t)r * D_N + d0 + dd) = w;
    }

    {
        int r = t & 127, dh = t >> 7;
        float p = 0.f;
        #pragma unroll 8
        for (int k = 0; k < 64; ++k) {
            int d = dh * 64 + k;
            p += sMu[d] * (float)T[r][d];
        }
        atomicAdd(&m_c[c * R_N + r], p);
    }
}

// ---------------------------------------------------------------------------
// gram: G[c] = B_c^T B_c in bf16 from basesT. grid (2, 110) — column halves:
// block (hc, c) computes rows 0..128 x cols hc*64..hc*64+64. Each of 4 waves
// does a 64x32 subtile. Doubles CU coverage vs one-block-per-class.
// ---------------------------------------------------------------------------
__global__ __launch_bounds__(256)
void gram(const bf16* __restrict__ basesT, bf16* __restrict__ G)
{
    const int hc = blockIdx.x, c = blockIdx.y;
    const bf16* Tc = basesT + (size_t)c * R_N * D_N;
    __shared__ bf16 sT[128][72];
    const int tid = threadIdx.x, wave = tid >> 6, lane = tid & 63;
    const int quad = lane >> 4, l15 = lane & 15;
    const int wr = (wave >> 1) * 64;               // 0 / 64
    const int wc = hc * 64 + (wave & 1) * 32;      // 32-col strip

    f32x4 acc[4][2];
    #pragma unroll
    for (int i = 0; i < 4; ++i)
        #pragma unroll
        for (int j = 0; j < 2; ++j) acc[i][j] = (f32x4)0.0f;

    for (int k0 = 0; k0 < D_N; k0 += 64) {
        __syncthreads();
        #pragma unroll
        for (int p = 0; p < 4; ++p) {
            int q = p * 256 + tid, row = q >> 3, u = q & 7;
            *(uint4*)(&sT[row][u * 8]) = *(const uint4*)(Tc + (size_t)row * D_N + k0 + u * 8);
        }
        __syncthreads();
        #pragma unroll
        for (int kk = 0; kk < 64; kk += 32) {
            bf16x8 af[4], bg[2];
            #pragma unroll
            for (int i = 0; i < 4; ++i) af[i] = *(const bf16x8*)(&sT[wr + 16 * i + l15][kk + quad * 8]);
            #pragma unroll
            for (int j = 0; j < 2; ++j) bg[j] = *(const bf16x8*)(&sT[wc + 16 * j + l15][kk + quad * 8]);
            #pragma unroll
            for (int i = 0; i < 4; ++i)
                #pragma unroll
                for (int j = 0; j < 2; ++j)
                    acc[i][j] = __builtin_amdgcn_mfma_f32_16x16x32_bf16(af[i], bg[j], acc[i][j], 0, 0, 0);
        }
    }
    #pragma unroll
    for (int i = 0; i < 4; ++i)
        #pragma unroll
        for (int j = 0; j < 2; ++j)
            #pragma unroll
            for (int reg = 0; reg < 4; ++reg) {
                int r = wr + 16 * i + quad * 4 + reg;
                int s = wc + 16 * j + l15;
                G[(size_t)c * 16384 + (size_t)r * 128 + s] = (bf16)acc[i][j][reg];
            }
}

// ---------------------------------------------------------------------------
// main_dist: coeff = z*B - m_c (MFMA), par/cnorm, zdot (VALU, co-issued),
// H = coeff*G (MFMA), qsum, dist. grid (4, 110), block 256.  [R4 version]
// ---------------------------------------------------------------------------
#define PADC 136
#define SM_A   0
#define SM_B   18432
#define SM_G   0
#define SM_C   36864
#define SM_M   (36864 + 34816)        // 71680
#define SM_INV (SM_M + 512)           // 72192
#define SM_PAR (SM_INV + 512)         // 72704
#define SM_CN  (SM_PAR + 512)         // 73216
#define SM_Q   (SM_CN + 512)          // 73728
#define SM_T2  (SM_Q + 512)           // 74240 : 768 f32 (par|cn|zdot)
#define SM_MU  (SM_T2 + 3072)         // 77312 : 768 bf16
#define SM_SZ  (SM_MU + 1536)         // 78848 B -> 2 blocks/CU

__global__ __launch_bounds__(256, 2)
void main_dist(const bf16* __restrict__ zbf, const bf16* __restrict__ basesT,
               const bf16* __restrict__ G, const float* __restrict__ m_c,
               const float* __restrict__ cur_vars, const float* __restrict__ old_vars,
               const float* __restrict__ cur_means, const float* __restrict__ old_means,
               const float* __restrict__ znorm, const float* __restrict__ munorm,
               float* __restrict__ gdist)
{
    const int mt = blockIdx.x, c = blockIdx.y;
    const int b0 = mt * 128;
    const float* vars = (c < C_NEW) ? cur_vars + (size_t)c * (R_N + 1)
                                    : old_vars + (size_t)(c - C_NEW) * (R_N + 1);
    const float* mu = (c < C_NEW) ? cur_means + (size_t)c * D_N
                                  : old_means + (size_t)(c - C_NEW) * D_N;
    __shared__ __align__(16) unsigned char smem[SM_SZ];
    bf16*  sA   = (bf16*)(smem + SM_A);
    bf16*  sB   = (bf16*)(smem + SM_B);
    bf16*  sG   = (bf16*)(smem + SM_G);
    bf16*  sC   = (bf16*)(smem + SM_C);
    float* sM   = (float*)(smem + SM_M);
    float* sInv = (float*)(smem + SM_INV);
    float* sPar = (float*)(smem + SM_PAR);
    float* sCn  = (float*)(smem + SM_CN);
    float* sQ   = (float*)(smem + SM_Q);
    float* sT2  = (float*)(smem + SM_T2);
    bf16*  sMuB = (bf16*)(smem + SM_MU);

    const int tid = threadIdx.x, wave = tid >> 6, lane = tid & 63;
    const int quad = lane >> 4, l15 = lane & 15;
    const int wr = (wave >> 1) * 64, wc = (wave & 1) * 64;

    if (tid < 128) {
        sM[tid]   = m_c[c * R_N + tid];
        sInv[tid] = 1.0f / fmaxf(vars[tid], VAR_FLOOR_F);
        sQ[tid]   = 0.0f;
    }
    for (int i = tid; i < D_N; i += 256) sMuB[i] = (bf16)mu[i];

    // ---- GEMM1: coeff_raw = z_tile * B_c ; zdot via VALU alongside ----
    f32x4 acc1[4][4];
    #pragma unroll
    for (int i = 0; i < 4; ++i)
        #pragma unroll
        for (int j = 0; j < 4; ++j) acc1[i][j] = (f32x4)0.0f;
    float zd = 0.f;
    const int zrow = tid >> 1, zhalf = tid & 1;

    const bf16* Az = zbf + (size_t)b0 * D_N;
    const bf16* Bb = basesT + (size_t)c * R_N * D_N;
    for (int k0 = 0; k0 < D_N; k0 += 64) {
        __syncthreads();
        #pragma unroll
        for (int p = 0; p < 4; ++p) {
            int q = p * 256 + tid, row = q >> 3, u = q & 7;
            *(uint4*)(sA + row * 72 + u * 8) = *(const uint4*)(Az + (size_t)row * D_N + k0 + u * 8);
            *(uint4*)(sB + row * 72 + u * 8) = *(const uint4*)(Bb + (size_t)row * D_N + k0 + u * 8);
        }
        __syncthreads();
        #pragma unroll
        for (int kk = 0; kk < 64; kk += 32) {
            bf16x8 af[4], bg[4];
            #pragma unroll
            for (int i = 0; i < 4; ++i) af[i] = *(const bf16x8*)(sA + (wr + 16 * i + l15) * 72 + kk + quad * 8);
            #pragma unroll
            for (int j = 0; j < 4; ++j) bg[j] = *(const bf16x8*)(sB + (wc + 16 * j + l15) * 72 + kk + quad * 8);
            #pragma unroll
            for (int i = 0; i < 4; ++i)
                #pragma unroll
                for (int j = 0; j < 4; ++j)
                    acc1[i][j] = __builtin_amdgcn_mfma_f32_16x16x32_bf16(af[i], bg[j], acc1[i][j], 0, 0, 0);
        }
        // zdot partial: row zrow, k-half zhalf of this 64-chunk
        {
            const bf16* zr = sA + zrow * 72 + zhalf * 32;
            const bf16* mr = sMuB + k0 + zhalf * 32;
            #pragma unroll
            for (int m = 0; m < 4; ++m) {
                bf16x8 a = *(const bf16x8*)(zr + m * 8);
                bf16x8 b = *(const bf16x8*)(mr + m * 8);
                #pragma unroll
                for (int e = 0; e < 8; ++e) zd += (float)a[e] * (float)b[e];
            }
        }
    }
    sT2[512 + tid] = zd;

    // ---- subtract m_c; keep f32 in regs; write bf16 coeff to sC ----
    #pragma unroll
    for (int j = 0; j < 4; ++j) {
        float mcv = sM[wc + 16 * j + l15];
        #pragma unroll
        for (int i = 0; i < 4; ++i)
            #pragma unroll
            for (int reg = 0; reg < 4; ++reg) {
                float cv = acc1[i][j][reg] - mcv;
                acc1[i][j][reg] = cv;
                int row = wr + 16 * i + quad * 4 + reg;
                int col = wc + 16 * j + l15;
                sC[row * PADC + col] = (bf16)cv;
            }
    }
    __syncthreads();

    // ---- par / cnorm per row (from bf16 coeff) + stage G into sG ----
    {
        int row = tid >> 1, half = tid & 1;
        float par = 0.f, cn = 0.f;
        #pragma unroll
        for (int m = 0; m < 8; ++m) {
            bf16x8 v = *(const bf16x8*)(sC + row * PADC + half * 64 + m * 8);
            #pragma unroll
            for (int e = 0; e < 8; ++e) {
                float f = (float)v[e];
                int col = half * 64 + m * 8 + e;
                cn  += f * f;
                par += f * f * sInv[col];
            }
        }
        sT2[tid] = par;
        sT2[256 + tid] = cn;
    }
    #pragma unroll
    for (int p = 0; p < 8; ++p) {
        int q = p * 256 + tid, s = q >> 4, u = q & 15;
        *(uint4*)(sG + s * PADC + u * 8) = *(const uint4*)(G + (size_t)c * 16384 + (size_t)s * 128 + u * 8);
    }
    __syncthreads();
    if (tid < 128) {
        sPar[tid] = sT2[tid * 2] + sT2[tid * 2 + 1];
        sCn[tid]  = sT2[256 + tid * 2] + sT2[256 + tid * 2 + 1];
    }

    // ---- GEMM2: H = coeff * G  (K=128) ----
    f32x4 acc2[4][4];
    #pragma unroll
    for (int i = 0; i < 4; ++i)
        #pragma unroll
        for (int j = 0; j < 4; ++j) acc2[i][j] = (f32x4)0.0f;
    #pragma unroll
    for (int kc = 0; kc < 128; kc += 32) {
        bf16x8 af[4], bg[4];
        #pragma unroll
        for (int i = 0; i < 4; ++i) af[i] = *(const bf16x8*)(sC + (wr + 16 * i + l15) * PADC + kc + quad * 8);
        #pragma unroll
        for (int j = 0; j < 4; ++j) bg[j] = *(const bf16x8*)(sG + (wc + 16 * j + l15) * PADC + kc + quad * 8);
        #pragma unroll
        for (int i = 0; i < 4; ++i)
            #pragma unroll
            for (int j = 0; j < 4; ++j)
                acc2[i][j] = __builtin_amdgcn_mfma_f32_16x16x32_bf16(af[i], bg[j], acc2[i][j], 0, 0, 0);
    }

    // ---- qsum[row] = sum_s H[row][s] * coeff[row][s] ----
    #pragma unroll
    for (int i = 0; i < 4; ++i)
        #pragma unroll
        for (int reg = 0; reg < 4; ++reg) {
            float qp = 0.f;
            #pragma unroll
            for (int j = 0; j < 4; ++j) qp += acc2[i][j][reg] * acc1[i][j][reg];
            qp += __shfl_xor(qp, 1, 64);
            qp += __shfl_xor(qp, 2, 64);
            qp += __shfl_xor(qp, 4, 64);
            qp += __shfl_xor(qp, 8, 64);
            if (l15 == 0) atomicAdd(&sQ[wr + 16 * i + quad * 4 + reg], qp);
        }
    __syncthreads();

    // ---- final dist per row ----
    if (tid < 128) {
        int b = b0 + tid;
        float zdot = sT2[512 + tid * 2] + sT2[512 + tid * 2 + 1];
        float nd2 = znorm[b] - 2.0f * zdot + munorm[c];
        float res = fmaxf(vars[R_N], VAR_FLOOR_F);
        float dist = (sPar[tid] + (nd2 - 2.0f * sCn[tid] + sQ[tid]) / res) / (float)D_N;
        if (!isfinite(dist)) dist = BIG_F;
        gdist[(size_t)b * C_TOT + c] = dist;
    }
}

// ---------------------------------------------------------------------------
// finalize_stage1: one thread per batch row (contiguous 440B row, L2-hot).
// ---------------------------------------------------------------------------
__global__ __launch_bounds__(64)
void finalize_stage1(const float* __restrict__ gdist,
                     const int* __restrict__ labels,
                     const int* __restrict__ ncid,
                     float* __restrict__ acc)
{
    const int b = blockIdx.x * 64 + threadIdx.x;
    const float* row = gdist + (size_t)b * C_TOT;
    float mn = 3.4e38f;
    #pragma unroll
    for (int cc = C_NEW; cc < C_TOT; ++cc) mn = fminf(mn, row[cc]);
    const int lab = labels[b];
    #pragma unroll
    for (int k = 0; k < C_NEW; ++k) {
        if (lab == ncid[k]) {
            int col = min(max(ncid[k], 0), C_TOT - 1);
            float ow = row[col];
            atomicAdd(&acc[k * 4 + 0], 1.0f);
            atomicAdd(&acc[k * 4 + 1], fmaxf(0.0f, MARGIN_F + ow - mn));
            atomicAdd(&acc[k * 4 + 2], ow);
            atomicAdd(&acc[k * 4 + 3], mn);
        }
    }
}

__global__ __launch_bounds__(64)
void finalize_stage2(const float* __restrict__ acc, float* __restrict__ out)
{
    if (threadIdx.x == 0) {
        float total = 0.f, own = 0.f, old = 0.f, nv = 0.f;
        #pragma unroll
        for (int k = 0; k < C_NEW; ++k) {
            float cnt = acc[k * 4 + 0];
            float den = fmaxf(cnt, 1.0f);
            if (cnt > 0.f) {
                nv += 1.f;
                total += acc[k * 4 + 1] / den;
                own   += acc[k * 4 + 2] / den;
                old   += acc[k * 4 + 3] / den;
            }
        }
        float nvd = fmaxf(nv, 1.0f);
        out[0] = total / nvd;
        out[1] = own / nvd;
        out[2] = old / nvd;
    }
}

// ---------------------------------------------------------------------------
// workspace layout (bytes):
//   gdist  @ 0        : 225280
//   zbf    @ 225280   : 786432
//   znorm  @ 1011712  : 2048
//   munorm @ 1013760  : 512
//   m_c    @ 1014272  : 56320
//   acc    @ 1070592  : 256      (zeroed together with m_c)
//   basesT @ 1070848  : 21626880
//   G      @ 22697728 : 3604480  -> total ~26.3 MB
// ---------------------------------------------------------------------------
extern "C" void kernel_launch(void* const* d_in, const int* in_sizes, int n_in,
                              void* d_out, int out_size, void* d_ws, size_t ws_size,
                              hipStream_t stream)
{
    const float* features  = (const float*)d_in[0];
    const int*   labels    = (const int*)d_in[1];
    const int*   ncid      = (const int*)d_in[2];
    const float* cur_means = (const float*)d_in[3];
    const float* cur_bases = (const float*)d_in[4];
    const float* cur_vars  = (const float*)d_in[5];
    const float* old_means = (const float*)d_in[6];
    const float* old_bases = (const float*)d_in[7];
    const float* old_vars  = (const float*)d_in[8];

    unsigned char* ws = (unsigned char*)d_ws;
    float* gdist  = (float*)(ws + 0);
    bf16*  zbf    = (bf16*) (ws + 225280);
    float* znorm  = (float*)(ws + 1011712);
    float* munorm = (float*)(ws + 1013760);
    float* m_c    = (float*)(ws + 1014272);
    float* acc    = (float*)(ws + 1070592);
    bf16*  basesT = (bf16*) (ws + 1070848);
    bf16*  G      = (bf16*) (ws + 22697728);

    hipMemsetAsync(m_c, 0, 56320 + 256, stream);   // m_c + acc

    prep_zmu<<<dim3(128 + C_TOT), dim3(256), 0, stream>>>(features, cur_means, old_means,
                                                          zbf, znorm, munorm);
    transpose_mc<<<dim3(6, C_TOT), dim3(256), 0, stream>>>(cur_bases, old_bases,
                                                           cur_means, old_means,
                                                           basesT, m_c);
    gram<<<dim3(2, C_TOT), dim3(256), 0, stream>>>(basesT, G);
    main_dist<<<dim3(4, C_TOT), dim3(256), 0, stream>>>(zbf, basesT, G, m_c,
                                                        cur_vars, old_vars,
                                                        cur_means, old_means,
                                                        znorm, munorm, gdist);
    finalize_stage1<<<dim3(8), dim3(64), 0, stream>>>(gdist, labels, ncid, acc);
    finalize_stage2<<<dim3(1), dim3(64), 0, stream>>>(acc, (float*)d_out);
}